// Round 2
// baseline (267.858 us; speedup 1.0000x reference)
//
#include <hip/hip_runtime.h>

#define SLEN 2048
#define PATCH 16
#define ND 4
#define NW 2033          // windows per dilation = S - P + 1
#define NCAND 8132       // ND * NW
#define NROWS 256        // B * C
#define NCH 8

// ws layout (bytes):
//   convd : double[NROWS*ND*SLEN]  @ 0            (16,777,216)
//   convf : float [NROWS*ND*SLEN]  @ 16777216     ( 8,388,608)
//   sel   : int   [NROWS*NCAND]    @ 25165824     ( 8,327,168)
//   nvalid: int   [NROWS]          @ 33492992     (     1,024)

__global__ __launch_bounds__(256) void k_conv(
    const float* __restrict__ seasonal,
    const float* __restrict__ conv_w,
    const float* __restrict__ conv_b,
    double* __restrict__ convd,
    float* __restrict__ convf)
{
    const int bid = blockIdx.x;
    const int row = bid >> 2;     // 0..255 (= b*8 + c)
    const int d   = bid & 3;      // dilation index
    const int dil = 1 << d;       // DILATIONS = (1,2,4,8)
    const int b = row >> 3, c = row & 7;

    __shared__ float xs[SLEN];
    #pragma unroll
    for (int j = 0; j < SLEN/256; ++j) {
        int s = threadIdx.x + j*256;
        xs[s] = seasonal[(size_t)(b*SLEN + s)*NCH + c];
    }
    double w[PATCH];
    #pragma unroll
    for (int k = 0; k < PATCH; ++k) w[k] = (double)conv_w[d*PATCH + k];
    const double bias = (double)conv_b[d];
    __syncthreads();

    const size_t obase = ((size_t)row*ND + d)*SLEN;
    #pragma unroll
    for (int j = 0; j < SLEN/256; ++j) {
        int t = threadIdx.x + j*256;
        double acc = 0.0;
        #pragma unroll
        for (int k = 0; k < PATCH; ++k) {
            int idx = t - (PATCH-1-k)*dil;   // idx <= t < SLEN; only left pad clips
            if (idx >= 0) acc += w[k] * (double)xs[idx];
        }
        acc += bias;
        convd[obase + t] = acc;
        convf[obase + t] = (float)acc;
    }
}

__device__ __forceinline__ void wstat(const double* __restrict__ cl, int idx,
                                      double& W1, double& W2, double& Wk)
{
    int d = (idx >= 3*NW) ? 3 : (idx >= 2*NW) ? 2 : (idx >= NW) ? 1 : 0;
    const double* p = cl + d*SLEN + (idx - d*NW);
    double a = 0.0, q = 0.0, ck = 0.0;
    #pragma unroll
    for (int k = 0; k < PATCH; ++k) {
        double v = p[k];
        a  += v;
        q   = fma(v, v, q);
        ck  = fma((double)k, v, ck);
    }
    W1 = a; W2 = q; Wk = ck;
}

__global__ __launch_bounds__(256) void k_merge(
    const double* __restrict__ convd,
    int* __restrict__ sel,
    int* __restrict__ nvalid)
{
    const int row = blockIdx.x;
    const int tid = threadIdx.x;

    __shared__ double cl[ND*SLEN];          // 64 KB: this row's conv outputs
    __shared__ unsigned char cma[8192];     // can_merge flags (padded to 8192)
    __shared__ unsigned char c0out[256];
    __shared__ unsigned char allone[256];
    __shared__ unsigned char cin[256];
    __shared__ unsigned sums[256];

    const double* crow = convd + (size_t)row*ND*SLEN;
    #pragma unroll
    for (int j = 0; j < (ND*SLEN)/256; ++j)
        cl[tid + j*256] = crow[tid + j*256];
    #pragma unroll
    for (int j = 0; j < 8192/256; ++j)
        cma[tid + j*256] = 0;
    __syncthreads();

    // Phase A: can_merge for pairs 0..8130 (stride-256 assignment: conflict-free LDS)
    for (int j = 0; j < 32; ++j) {
        int p = tid + j*256;
        if (p < NCAND - 1) {
            double aW1,aW2,aWk, bW1,bW2,bWk;
            wstat(cl, p,   aW1,aW2,aWk);
            wstat(cl, p+1, bW1,bW2,bWk);
            double S1  = aW1 + bW1;
            double S2  = aW2 + bW2;
            double Sxy = (aWk - 15.5*aW1) + (bWk + 0.5*bW1); // x-weights: k-15.5 / k+0.5
            double syy = S2 - S1*S1*(1.0/32.0);
            double r2  = (Sxy*Sxy) / (2728.0 * syy);          // sxx = 2728 exact
            cma[p] = (r2 >= 0.5) ? 1 : 0;
        }
    }
    __syncthreads();

    // Phase B: chunked scan. consumed' = cm & ~consumed forgets input at first cm=0;
    // all-ones 32-chunk toggles an even number of times -> identity.
    const int base = tid*32;
    unsigned cmbits = 0;
    #pragma unroll
    for (int w = 0; w < 32; ++w)
        cmbits |= ((unsigned)cma[base + w]) << w;

    unsigned consumed = 0;
    #pragma unroll
    for (int w = 0; w < 32; ++w) {
        unsigned bit = (cmbits >> w) & 1u;
        consumed = bit & (consumed ^ 1u);
    }
    c0out[tid]  = (unsigned char)consumed;
    allone[tid] = (cmbits == 0xFFFFFFFFu) ? 1 : 0;
    __syncthreads();

    if (tid == 0) {
        unsigned cc = 0;
        for (int t2 = 0; t2 < 256; ++t2) {
            cin[t2] = (unsigned char)cc;
            if (!allone[t2]) cc = c0out[t2];
        }
    }
    __syncthreads();

    // Phase C: exact merge/valid bits per chunk, count valids
    unsigned cons = cin[tid];
    unsigned validb = 0, mergeb = 0;
    int cnt = 0;
    const int nelem = (NCAND - base > 32) ? 32 : (NCAND - base); // may be <=0
    for (int w = 0; w < nelem; ++w) {
        unsigned bit = (cmbits >> w) & 1u;
        unsigned val = cons ^ 1u;     // valid = ~consumed
        unsigned mrg = bit & val;     // merge = cm & ~consumed
        validb |= val << w;
        mergeb |= mrg << w;
        cnt += (int)val;
        cons = mrg;
    }

    // block inclusive prefix sum over counts
    sums[tid] = (unsigned)cnt;
    __syncthreads();
    for (int off = 1; off < 256; off <<= 1) {
        unsigned v = (tid >= off) ? sums[tid - off] : 0u;
        __syncthreads();
        sums[tid] += v;
        __syncthreads();
    }
    if (tid == 255) nvalid[row] = (int)sums[255];

    unsigned r = sums[tid] - (unsigned)cnt;   // exclusive offset
    int* selrow = sel + (size_t)row*NCAND;
    for (int w = 0; w < nelem; ++w) {
        if ((validb >> w) & 1u) {
            selrow[r++] = ((base + w) << 1) | (int)((mergeb >> w) & 1u);
        }
    }
}

__global__ __launch_bounds__(256) void k_out(
    const float* __restrict__ convf,
    const int* __restrict__ sel,
    const int* __restrict__ nvalid,
    float* __restrict__ out)
{
    const unsigned gid    = blockIdx.x*256u + threadIdx.x;
    const unsigned slab   = gid >> 7;        // b*NCAND + n
    const unsigned within = gid & 127u;
    const unsigned k      = within >> 3;
    const unsigned c      = within & 7u;
    const unsigned b      = slab / NCAND;
    const unsigned n      = slab - b*NCAND;
    const unsigned row    = b*NCH + c;

    float v = 0.0f;
    if ((int)n < nvalid[row]) {
        int e = sel[(size_t)row*NCAND + n];
        int i = e >> 1;
        int d = (i >= 3*NW) ? 3 : (i >= 2*NW) ? 2 : (i >= NW) ? 1 : 0;
        const float* cf = convf + ((size_t)row*ND + d)*SLEN + (i - d*NW);
        v = cf[k];
        if (e & 1) {
            int i2 = i + 1;
            int d2 = (i2 >= 3*NW) ? 3 : (i2 >= 2*NW) ? 2 : (i2 >= NW) ? 1 : 0;
            const float* cf2 = convf + ((size_t)row*ND + d2)*SLEN + (i2 - d2*NW);
            v = 0.5f * (v + cf2[k]);
        }
    }
    out[gid] = v;   // gid == ((b*NCAND+n)*16 + k)*8 + c  -> fully coalesced
}

extern "C" void kernel_launch(void* const* d_in, const int* in_sizes, int n_in,
                              void* d_out, int out_size, void* d_ws, size_t ws_size,
                              hipStream_t stream) {
    const float* seasonal = (const float*)d_in[0];
    const float* conv_w   = (const float*)d_in[1];
    const float* conv_b   = (const float*)d_in[2];
    float* out = (float*)d_out;

    char* ws = (char*)d_ws;
    double* convd = (double*)(ws);
    float*  convf = (float*)(ws + 16777216);
    int*    sel   = (int*)(ws + 16777216 + 8388608);
    int*    nvld  = (int*)(ws + 16777216 + 8388608 + 8327168);

    hipLaunchKernelGGL(k_conv, dim3(NROWS*ND), dim3(256), 0, stream,
                       seasonal, conv_w, conv_b, convd, convf);
    hipLaunchKernelGGL(k_merge, dim3(NROWS), dim3(256), 0, stream,
                       convd, sel, nvld);
    hipLaunchKernelGGL(k_out, dim3(33308672/256), dim3(256), 0, stream,
                       convf, sel, nvld, out);
}

// Round 3
// 215.888 us; speedup vs baseline: 1.2407x; 1.2407x over previous
//
#include <hip/hip_runtime.h>

#define SLEN 2048
#define PATCH 16
#define ND 4
#define NW 2033          // windows per dilation = S - P + 1
#define NCAND 8132       // ND * NW
#define NROWS 256        // B * C
#define NCH 8
#define ROWPAD 8192      // padded per-row stride for cmb/sel

// ws layout (bytes):
//   convd : double[NROWS*ND*SLEN] @ 0         (16 MB)  [dead after k_cm]
//   convf : float [NROWS*ND*SLEN] @ 16777216  ( 8 MB)
//   cmb   : uchar [NROWS*ROWPAD]  @ 25165824  ( 2 MB)
//   sel   : int   [NROWS*ROWPAD]  @ 0         ( 8 MB, aliases dead convd)

__global__ __launch_bounds__(256) void k_conv(
    const float* __restrict__ seasonal,
    const float* __restrict__ conv_w,
    const float* __restrict__ conv_b,
    double* __restrict__ convd,
    float* __restrict__ convf)
{
    const int bid = blockIdx.x;
    const int row = bid >> 2;     // 0..255 (= b*8 + c)
    const int d   = bid & 3;      // dilation index
    const int dil = 1 << d;       // DILATIONS = (1,2,4,8)
    const int b = row >> 3, c = row & 7;

    __shared__ float xs[SLEN];
    #pragma unroll
    for (int j = 0; j < SLEN/256; ++j) {
        int s = threadIdx.x + j*256;
        xs[s] = seasonal[(size_t)(b*SLEN + s)*NCH + c];
    }
    double w[PATCH];
    #pragma unroll
    for (int k = 0; k < PATCH; ++k) w[k] = (double)conv_w[d*PATCH + k];
    const double bias = (double)conv_b[d];
    __syncthreads();

    const size_t obase = ((size_t)row*ND + d)*SLEN;
    #pragma unroll
    for (int j = 0; j < SLEN/256; ++j) {
        int t = threadIdx.x + j*256;
        double acc = 0.0;
        #pragma unroll
        for (int k = 0; k < PATCH; ++k) {
            int idx = t - (PATCH-1-k)*dil;   // only left pad clips
            if (idx >= 0) acc += w[k] * (double)xs[idx];
        }
        acc += bias;
        convd[obase + t] = acc;
        convf[obase + t] = (float)acc;
    }
}

// can_merge bytes via sliding-window stats. One block per (row, dilation).
__global__ __launch_bounds__(256) void k_cm(
    const double* __restrict__ convd,
    unsigned char* __restrict__ cmb)
{
    const int row = blockIdx.x >> 2;
    const int d   = blockIdx.x & 3;
    const int tid = threadIdx.x;
    const double* g = convd + ((size_t)row*ND + d)*SLEN;
    unsigned char* crow = cmb + (size_t)row*ROWPAD + d*NW;

    if (tid < 254) {
        const int w0 = tid*8;      // windows w0..w0+8, pairs w0..w0+7 (max 2031)
        double W1=0.0, W2=0.0, Wk=0.0;
        #pragma unroll
        for (int k = 0; k < 16; ++k) {
            double v = g[w0+k];
            W1 += v; W2 = fma(v,v,W2); Wk = fma((double)k,v,Wk);
        }
        unsigned char bits[8];
        #pragma unroll
        for (int j = 0; j < 8; ++j) {
            double v0 = g[w0+j], v16 = g[w0+j+16];
            double nW1 = W1 + (v16 - v0);
            double nW2 = W2 + (v16*v16 - v0*v0);
            double nWk = Wk - W1 + v0 + 15.0*v16;
            double S1  = W1 + nW1;
            double S2  = W2 + nW2;
            double Sxy = (Wk - 15.5*W1) + (nWk + 0.5*nW1);
            double syy = S2 - S1*S1*(1.0/32.0);
            bits[j] = (unsigned char)((Sxy*Sxy >= 1364.0*syy) && (syy > 0.0));
            W1 = nW1; W2 = nW2; Wk = nWk;
        }
        #pragma unroll
        for (int j = 0; j < 8; ++j) crow[w0+j] = bits[j];
    } else if (tid == 254 && d < 3) {
        // cross-dilation boundary pair: windows (d,2032) and (d+1,0)
        const double* g2 = convd + ((size_t)row*ND + d + 1)*SLEN;
        double aW1=0,aW2=0,aWk=0, bW1=0,bW2=0,bWk=0;
        #pragma unroll
        for (int k = 0; k < 16; ++k) {
            double va = g[2032+k]; aW1 += va; aW2 = fma(va,va,aW2); aWk = fma((double)k,va,aWk);
            double vb = g2[k];     bW1 += vb; bW2 = fma(vb,vb,bW2); bWk = fma((double)k,vb,bWk);
        }
        double S1  = aW1 + bW1;
        double S2  = aW2 + bW2;
        double Sxy = (aWk - 15.5*aW1) + (bWk + 0.5*bW1);
        double syy = S2 - S1*S1*(1.0/32.0);
        crow[2032] = (unsigned char)((Sxy*Sxy >= 1364.0*syy) && (syy > 0.0));
    }
}

// scan + stable compaction per row; writes sel (+ -1 sentinel tail)
__global__ __launch_bounds__(256) void k_pack(
    const unsigned char* __restrict__ cmb,
    int* __restrict__ sel)
{
    const int row = blockIdx.x;
    const int tid = threadIdx.x;
    __shared__ unsigned char c0out[256];
    __shared__ int pmax[256];
    __shared__ unsigned sums[256];

    // 32 cm bytes -> 32 bits (mask p >= NCAND-1: pad-false + poison tail)
    const unsigned* cmw = (const unsigned*)(cmb + (size_t)row*ROWPAD);
    unsigned cmbits = 0;
    #pragma unroll
    for (int q = 0; q < 8; ++q) {
        unsigned wrd = cmw[tid*8 + q];
        #pragma unroll
        for (int bb = 0; bb < 4; ++bb) {
            int p = tid*32 + q*4 + bb;
            unsigned bit = ((wrd >> (8*bb)) & 0xffu) ? 1u : 0u;
            if (p >= NCAND-1) bit = 0;
            cmbits |= bit << (q*4 + bb);
        }
    }

    // chunk function: consumed' = cm & ~consumed forgets carry at first cm=0;
    // all-ones chunk (even length 32) is identity.
    unsigned consumed = 0;
    #pragma unroll
    for (int w = 0; w < 32; ++w) {
        unsigned bit = (cmbits >> w) & 1u;
        consumed = bit & (consumed ^ 1u);
    }
    c0out[tid] = (unsigned char)consumed;
    pmax[tid]  = (cmbits == 0xFFFFFFFFu) ? -1 : tid;   // last non-identity chunk
    __syncthreads();
    for (int off = 1; off < 256; off <<= 1) {          // inclusive prefix-max
        int v = (tid >= off) ? pmax[tid-off] : -1;
        __syncthreads();
        if (v > pmax[tid]) pmax[tid] = v;
        __syncthreads();
    }
    unsigned carry = 0;
    if (tid > 0) { int m = pmax[tid-1]; if (m >= 0) carry = c0out[m]; }

    // exact merge/valid bits with carry-in
    unsigned cons = carry;
    unsigned validb = 0, mergeb = 0;
    int cnt = 0;
    const int base = tid*32;
    int nelem = NCAND - base; if (nelem > 32) nelem = 32; if (nelem < 0) nelem = 0;
    for (int w = 0; w < nelem; ++w) {
        unsigned bit = (cmbits >> w) & 1u;
        unsigned val = cons ^ 1u;
        unsigned mrg = bit & val;
        validb |= val << w;
        mergeb |= mrg << w;
        cnt += (int)val;
        cons = mrg;
    }

    sums[tid] = (unsigned)cnt;
    __syncthreads();
    for (int off = 1; off < 256; off <<= 1) {
        unsigned v = (tid >= off) ? sums[tid-off] : 0u;
        __syncthreads();
        sums[tid] += v;
        __syncthreads();
    }
    unsigned r = sums[tid] - (unsigned)cnt;
    unsigned total = sums[255];
    int* selrow = sel + (size_t)row*ROWPAD;
    for (int w = 0; w < nelem; ++w) {
        if ((validb >> w) & 1u)
            selrow[r++] = ((base + w) << 1) | (int)((mergeb >> w) & 1u);
    }
    for (int idx = (int)total + tid; idx < ROWPAD; idx += 256)
        selrow[idx] = -1;   // sentinel tail: k_out needs no nvalid
}

__global__ __launch_bounds__(256) void k_out(
    const float* __restrict__ convf,
    const int* __restrict__ sel,
    float* __restrict__ out)
{
    const unsigned h = blockIdx.x;
    const unsigned l = (h & 7u)*4066u + (h >> 3);   // consecutive-n blocks -> same XCD
    const unsigned base = l*1024u + threadIdx.x;

    int e[4]; unsigned gid[4], row4[4];
    #pragma unroll
    for (int j = 0; j < 4; ++j) {
        unsigned g = base + j*256u;
        gid[j] = g;
        unsigned slab = g >> 7, within = g & 127u;
        unsigned c = within & 7u;
        unsigned b = slab / NCAND, n = slab - b*NCAND;
        row4[j] = b*NCH + c;
        e[j] = sel[(size_t)row4[j]*ROWPAD + n];
    }
    float v[4];
    #pragma unroll
    for (int j = 0; j < 4; ++j) {
        unsigned g = gid[j];
        unsigned k = (g & 127u) >> 3;
        int ee = (e[j] < 0) ? 0 : e[j];
        int i  = ee >> 1;
        int i2 = i + 1; if (i2 > NCAND-1) i2 = NCAND-1;
        int d  = (i  >= 3*NW) ? 3 : (i  >= 2*NW) ? 2 : (i  >= NW) ? 1 : 0;
        int d2 = (i2 >= 3*NW) ? 3 : (i2 >= 2*NW) ? 2 : (i2 >= NW) ? 1 : 0;
        const float* cf = convf + (size_t)row4[j]*8192;
        float a  = cf[i  + 15*d  + (int)k];   // row*8192 + d*2048 + (i - d*NW) + k
        float bb = cf[i2 + 15*d2 + (int)k];
        float m  = (ee & 1) ? 0.5f*(a + bb) : a;
        v[j] = (e[j] < 0) ? 0.0f : m;
    }
    #pragma unroll
    for (int j = 0; j < 4; ++j) out[gid[j]] = v[j];
}

extern "C" void kernel_launch(void* const* d_in, const int* in_sizes, int n_in,
                              void* d_out, int out_size, void* d_ws, size_t ws_size,
                              hipStream_t stream) {
    const float* seasonal = (const float*)d_in[0];
    const float* conv_w   = (const float*)d_in[1];
    const float* conv_b   = (const float*)d_in[2];
    float* out = (float*)d_out;

    char* ws = (char*)d_ws;
    double*        convd = (double*)(ws);
    float*         convf = (float*)(ws + 16777216);
    unsigned char* cmb   = (unsigned char*)(ws + 25165824);
    int*           sel   = (int*)(ws);          // aliases convd (dead after k_cm)

    hipLaunchKernelGGL(k_conv, dim3(NROWS*ND), dim3(256), 0, stream,
                       seasonal, conv_w, conv_b, convd, convf);
    hipLaunchKernelGGL(k_cm,   dim3(NROWS*ND), dim3(256), 0, stream,
                       convd, cmb);
    hipLaunchKernelGGL(k_pack, dim3(NROWS), dim3(256), 0, stream,
                       cmb, sel);
    hipLaunchKernelGGL(k_out,  dim3(32528), dim3(256), 0, stream,
                       convf, sel, out);
}

// Round 4
// 182.625 us; speedup vs baseline: 1.4667x; 1.1821x over previous
//
#include <hip/hip_runtime.h>

#define SLEN 2048
#define PATCH 16
#define ND 4
#define NW 2033          // windows per dilation = S - P + 1
#define NCAND 8132       // ND * NW
#define NROWS 256        // B * C
#define NCH 8
#define ROWPAD 8192      // padded per-row stride for cmb/sel

// ws layout (bytes):
//   convd : double[NROWS*ND*SLEN] @ 0         (16 MB)  [dead after k_cm]
//   convf : float [NROWS*ND*SLEN] @ 16777216  ( 8 MB)
//   cmb   : uchar [NROWS*ROWPAD]  @ 25165824  ( 2 MB)
//   sel   : int   [NROWS*ROWPAD]  @ 0         ( 8 MB, aliases dead convd)

__global__ __launch_bounds__(256) void k_conv(
    const float* __restrict__ seasonal,
    const float* __restrict__ conv_w,
    const float* __restrict__ conv_b,
    double* __restrict__ convd,
    float* __restrict__ convf)
{
    const int bid = blockIdx.x;
    const int row = bid >> 2;     // 0..255 (= b*8 + c)
    const int d   = bid & 3;      // dilation index
    const int dil = 1 << d;       // DILATIONS = (1,2,4,8)
    const int b = row >> 3, c = row & 7;

    __shared__ float xs[SLEN];
    #pragma unroll
    for (int j = 0; j < SLEN/256; ++j) {
        int s = threadIdx.x + j*256;
        xs[s] = seasonal[(size_t)(b*SLEN + s)*NCH + c];
    }
    double w[PATCH];
    #pragma unroll
    for (int k = 0; k < PATCH; ++k) w[k] = (double)conv_w[d*PATCH + k];
    const double bias = (double)conv_b[d];
    __syncthreads();

    const size_t obase = ((size_t)row*ND + d)*SLEN;
    #pragma unroll
    for (int j = 0; j < SLEN/256; ++j) {
        int t = threadIdx.x + j*256;
        double acc = 0.0;
        #pragma unroll
        for (int k = 0; k < PATCH; ++k) {
            int idx = t - (PATCH-1-k)*dil;   // only left pad clips
            if (idx >= 0) acc += w[k] * (double)xs[idx];
        }
        acc += bias;
        convd[obase + t] = acc;
        convf[obase + t] = (float)acc;
    }
}

// can_merge bytes via sliding-window stats. One block per (row, dilation).
__global__ __launch_bounds__(256) void k_cm(
    const double* __restrict__ convd,
    unsigned char* __restrict__ cmb)
{
    const int row = blockIdx.x >> 2;
    const int d   = blockIdx.x & 3;
    const int tid = threadIdx.x;
    const double* g = convd + ((size_t)row*ND + d)*SLEN;
    unsigned char* crow = cmb + (size_t)row*ROWPAD + d*NW;

    if (tid < 254) {
        const int w0 = tid*8;      // windows w0..w0+8, pairs w0..w0+7 (max 2031)
        double W1=0.0, W2=0.0, Wk=0.0;
        #pragma unroll
        for (int k = 0; k < 16; ++k) {
            double v = g[w0+k];
            W1 += v; W2 = fma(v,v,W2); Wk = fma((double)k,v,Wk);
        }
        unsigned char bits[8];
        #pragma unroll
        for (int j = 0; j < 8; ++j) {
            double v0 = g[w0+j], v16 = g[w0+j+16];
            double nW1 = W1 + (v16 - v0);
            double nW2 = W2 + (v16*v16 - v0*v0);
            double nWk = Wk - W1 + v0 + 15.0*v16;
            double S1  = W1 + nW1;
            double S2  = W2 + nW2;
            double Sxy = (Wk - 15.5*W1) + (nWk + 0.5*nW1);
            double syy = S2 - S1*S1*(1.0/32.0);
            bits[j] = (unsigned char)((Sxy*Sxy >= 1364.0*syy) && (syy > 0.0));
            W1 = nW1; W2 = nW2; Wk = nWk;
        }
        #pragma unroll
        for (int j = 0; j < 8; ++j) crow[w0+j] = bits[j];
    } else if (tid == 254 && d < 3) {
        // cross-dilation boundary pair: windows (d,2032) and (d+1,0)
        const double* g2 = convd + ((size_t)row*ND + d + 1)*SLEN;
        double aW1=0,aW2=0,aWk=0, bW1=0,bW2=0,bWk=0;
        #pragma unroll
        for (int k = 0; k < 16; ++k) {
            double va = g[2032+k]; aW1 += va; aW2 = fma(va,va,aW2); aWk = fma((double)k,va,aWk);
            double vb = g2[k];     bW1 += vb; bW2 = fma(vb,vb,bW2); bWk = fma((double)k,vb,bWk);
        }
        double S1  = aW1 + bW1;
        double S2  = aW2 + bW2;
        double Sxy = (aWk - 15.5*aW1) + (bWk + 0.5*bW1);
        double syy = S2 - S1*S1*(1.0/32.0);
        crow[2032] = (unsigned char)((Sxy*Sxy >= 1364.0*syy) && (syy > 0.0));
    }
}

// scan + stable compaction per row; writes sel (+ -1 sentinel tail)
__global__ __launch_bounds__(256) void k_pack(
    const unsigned char* __restrict__ cmb,
    int* __restrict__ sel)
{
    const int row = blockIdx.x;
    const int tid = threadIdx.x;
    __shared__ unsigned char c0out[256];
    __shared__ int pmax[256];
    __shared__ unsigned sums[256];

    // 32 cm bytes -> 32 bits (mask p >= NCAND-1: pad-false + poison tail)
    const unsigned* cmw = (const unsigned*)(cmb + (size_t)row*ROWPAD);
    unsigned cmbits = 0;
    #pragma unroll
    for (int q = 0; q < 8; ++q) {
        unsigned wrd = cmw[tid*8 + q];
        #pragma unroll
        for (int bb = 0; bb < 4; ++bb) {
            int p = tid*32 + q*4 + bb;
            unsigned bit = ((wrd >> (8*bb)) & 0xffu) ? 1u : 0u;
            if (p >= NCAND-1) bit = 0;
            cmbits |= bit << (q*4 + bb);
        }
    }

    // chunk function: consumed' = cm & ~consumed forgets carry at first cm=0;
    // all-ones chunk (even length 32) is identity.
    unsigned consumed = 0;
    #pragma unroll
    for (int w = 0; w < 32; ++w) {
        unsigned bit = (cmbits >> w) & 1u;
        consumed = bit & (consumed ^ 1u);
    }
    c0out[tid] = (unsigned char)consumed;
    pmax[tid]  = (cmbits == 0xFFFFFFFFu) ? -1 : tid;   // last non-identity chunk
    __syncthreads();
    for (int off = 1; off < 256; off <<= 1) {          // inclusive prefix-max
        int v = (tid >= off) ? pmax[tid-off] : -1;
        __syncthreads();
        if (v > pmax[tid]) pmax[tid] = v;
        __syncthreads();
    }
    unsigned carry = 0;
    if (tid > 0) { int m = pmax[tid-1]; if (m >= 0) carry = c0out[m]; }

    // exact merge/valid bits with carry-in
    unsigned cons = carry;
    unsigned validb = 0, mergeb = 0;
    int cnt = 0;
    const int base = tid*32;
    int nelem = NCAND - base; if (nelem > 32) nelem = 32; if (nelem < 0) nelem = 0;
    for (int w = 0; w < nelem; ++w) {
        unsigned bit = (cmbits >> w) & 1u;
        unsigned val = cons ^ 1u;
        unsigned mrg = bit & val;
        validb |= val << w;
        mergeb |= mrg << w;
        cnt += (int)val;
        cons = mrg;
    }

    sums[tid] = (unsigned)cnt;
    __syncthreads();
    for (int off = 1; off < 256; off <<= 1) {
        unsigned v = (tid >= off) ? sums[tid-off] : 0u;
        __syncthreads();
        sums[tid] += v;
        __syncthreads();
    }
    unsigned r = sums[tid] - (unsigned)cnt;
    unsigned total = sums[255];
    int* selrow = sel + (size_t)row*ROWPAD;
    for (int w = 0; w < nelem; ++w) {
        if ((validb >> w) & 1u)
            selrow[r++] = ((base + w) << 1) | (int)((mergeb >> w) & 1u);
    }
    for (int idx = (int)total + tid; idx < ROWPAD; idx += 256)
        selrow[idx] = -1;   // sentinel tail: k_out needs no nvalid
}

// One thread per (slab, channel): produces all 16 patch values.
// Windows i and i+1 overlap by 15 within a dilation -> 17 contiguous floats
// serve both sides of a merge. Cross-dilation merge (3 i-values/row) is rare.
__global__ __launch_bounds__(256) void k_out(
    const float* __restrict__ convf,
    const int* __restrict__ sel,
    float* __restrict__ out)
{
    const int t = threadIdx.x;
    const int c = t & 7;
    const int s = t >> 3;                        // 0..31
    const unsigned slab = blockIdx.x*32u + (unsigned)s;  // b*NCAND + n
    const unsigned b = slab / NCAND;
    const unsigned n = slab - b*NCAND;
    const unsigned row = b*NCH + (unsigned)c;

    const int e = sel[(size_t)row*ROWPAD + n];
    float* o = out + (size_t)slab*128 + c;       // out[((slab)*16+k)*8+c]

    if (e < 0) {
        #pragma unroll
        for (int k = 0; k < 16; ++k) o[k*8] = 0.0f;
        return;
    }
    const int i = e >> 1;
    const int d = (i >= 3*NW) ? 3 : (i >= 2*NW) ? 2 : (i >= NW) ? 1 : 0;
    const float* cf = convf + (size_t)row*8192 + i + 15*d;  // row base + d*2048 + (i-d*NW)
    float f[17];
    #pragma unroll
    for (int k = 0; k < 17; ++k) f[k] = cf[k];   // f[16] only used for same-dil merge
    if (e & 1) {
        const int i2 = i + 1;                    // merge at i=NCAND-1 masked off in k_pack
        const int d2 = (i2 >= 3*NW) ? 3 : (i2 >= 2*NW) ? 2 : (i2 >= NW) ? 1 : 0;
        if (d2 != d) {                           // cross-dilation neighbor window
            const float* cg = convf + (size_t)row*8192 + i2 + 15*d2;
            #pragma unroll
            for (int k = 0; k < 16; ++k) o[k*8] = 0.5f*(f[k] + cg[k]);
        } else {
            #pragma unroll
            for (int k = 0; k < 16; ++k) o[k*8] = 0.5f*(f[k] + f[k+1]);
        }
    } else {
        #pragma unroll
        for (int k = 0; k < 16; ++k) o[k*8] = f[k];
    }
}

extern "C" void kernel_launch(void* const* d_in, const int* in_sizes, int n_in,
                              void* d_out, int out_size, void* d_ws, size_t ws_size,
                              hipStream_t stream) {
    const float* seasonal = (const float*)d_in[0];
    const float* conv_w   = (const float*)d_in[1];
    const float* conv_b   = (const float*)d_in[2];
    float* out = (float*)d_out;

    char* ws = (char*)d_ws;
    double*        convd = (double*)(ws);
    float*         convf = (float*)(ws + 16777216);
    unsigned char* cmb   = (unsigned char*)(ws + 25165824);
    int*           sel   = (int*)(ws);          // aliases convd (dead after k_cm)

    hipLaunchKernelGGL(k_conv, dim3(NROWS*ND), dim3(256), 0, stream,
                       seasonal, conv_w, conv_b, convd, convf);
    hipLaunchKernelGGL(k_cm,   dim3(NROWS*ND), dim3(256), 0, stream,
                       convd, cmb);
    hipLaunchKernelGGL(k_pack, dim3(NROWS), dim3(256), 0, stream,
                       cmb, sel);
    // 32 B * NCAND slabs * 8 ch / (32 slabs * 8 ch per block) = 8132 blocks
    hipLaunchKernelGGL(k_out,  dim3(8132), dim3(256), 0, stream,
                       convf, sel, out);
}

// Round 5
// 177.783 us; speedup vs baseline: 1.5067x; 1.0272x over previous
//
#include <hip/hip_runtime.h>

#define SLEN 2048
#define PATCH 16
#define ND 4
#define NW 2033          // windows per dilation = S - P + 1
#define NCAND 8132       // ND * NW
#define NROWS 256        // B * C
#define NCH 8
#define ROWPAD 8192      // padded per-row stride for cmb/sel

// ws layout (bytes):
//   convd : double[NROWS*ND*SLEN] @ 0         (16 MB)  [dead after k_cm]
//   convf : float [NROWS*ND*SLEN] @ 16777216  ( 8 MB)
//   cmb   : uchar [NROWS*ROWPAD]  @ 25165824  ( 2 MB)
//   sel   : int   [NROWS*ROWPAD]  @ 0         ( 8 MB, aliases dead convd)

__global__ __launch_bounds__(256) void k_conv(
    const float* __restrict__ seasonal,
    const float* __restrict__ conv_w,
    const float* __restrict__ conv_b,
    double* __restrict__ convd,
    float* __restrict__ convf)
{
    const int bid = blockIdx.x;
    const int row = bid >> 2;     // 0..255 (= b*8 + c)
    const int d   = bid & 3;      // dilation index
    const int dil = 1 << d;       // DILATIONS = (1,2,4,8)
    const int b = row >> 3, c = row & 7;

    __shared__ float xs[SLEN];
    #pragma unroll
    for (int j = 0; j < SLEN/256; ++j) {
        int s = threadIdx.x + j*256;
        xs[s] = seasonal[(size_t)(b*SLEN + s)*NCH + c];
    }
    double w[PATCH];
    #pragma unroll
    for (int k = 0; k < PATCH; ++k) w[k] = (double)conv_w[d*PATCH + k];
    const double bias = (double)conv_b[d];
    __syncthreads();

    const size_t obase = ((size_t)row*ND + d)*SLEN;
    #pragma unroll
    for (int j = 0; j < SLEN/256; ++j) {
        int t = threadIdx.x + j*256;
        double acc = 0.0;
        #pragma unroll
        for (int k = 0; k < PATCH; ++k) {
            int idx = t - (PATCH-1-k)*dil;   // only left pad clips
            if (idx >= 0) acc += w[k] * (double)xs[idx];
        }
        acc += bias;
        convd[obase + t] = acc;
        convf[obase + t] = (float)acc;
    }
}

// can_merge bytes via sliding-window stats. One block per (row, dilation).
__global__ __launch_bounds__(256) void k_cm(
    const double* __restrict__ convd,
    unsigned char* __restrict__ cmb)
{
    const int row = blockIdx.x >> 2;
    const int d   = blockIdx.x & 3;
    const int tid = threadIdx.x;
    const double* g = convd + ((size_t)row*ND + d)*SLEN;
    unsigned char* crow = cmb + (size_t)row*ROWPAD + d*NW;

    if (tid < 254) {
        const int w0 = tid*8;      // windows w0..w0+8, pairs w0..w0+7 (max 2031)
        double W1=0.0, W2=0.0, Wk=0.0;
        #pragma unroll
        for (int k = 0; k < 16; ++k) {
            double v = g[w0+k];
            W1 += v; W2 = fma(v,v,W2); Wk = fma((double)k,v,Wk);
        }
        unsigned char bits[8];
        #pragma unroll
        for (int j = 0; j < 8; ++j) {
            double v0 = g[w0+j], v16 = g[w0+j+16];
            double nW1 = W1 + (v16 - v0);
            double nW2 = W2 + (v16*v16 - v0*v0);
            double nWk = Wk - W1 + v0 + 15.0*v16;
            double S1  = W1 + nW1;
            double S2  = W2 + nW2;
            double Sxy = (Wk - 15.5*W1) + (nWk + 0.5*nW1);
            double syy = S2 - S1*S1*(1.0/32.0);
            bits[j] = (unsigned char)((Sxy*Sxy >= 1364.0*syy) && (syy > 0.0));
            W1 = nW1; W2 = nW2; Wk = nWk;
        }
        #pragma unroll
        for (int j = 0; j < 8; ++j) crow[w0+j] = bits[j];
    } else if (tid == 254 && d < 3) {
        // cross-dilation boundary pair: windows (d,2032) and (d+1,0)
        const double* g2 = convd + ((size_t)row*ND + d + 1)*SLEN;
        double aW1=0,aW2=0,aWk=0, bW1=0,bW2=0,bWk=0;
        #pragma unroll
        for (int k = 0; k < 16; ++k) {
            double va = g[2032+k]; aW1 += va; aW2 = fma(va,va,aW2); aWk = fma((double)k,va,aWk);
            double vb = g2[k];     bW1 += vb; bW2 = fma(vb,vb,bW2); bWk = fma((double)k,vb,bWk);
        }
        double S1  = aW1 + bW1;
        double S2  = aW2 + bW2;
        double Sxy = (aWk - 15.5*aW1) + (bWk + 0.5*bW1);
        double syy = S2 - S1*S1*(1.0/32.0);
        crow[2032] = (unsigned char)((Sxy*Sxy >= 1364.0*syy) && (syy > 0.0));
    }
}

// scan + stable compaction per row; writes sel (+ -1 sentinel tail)
__global__ __launch_bounds__(256) void k_pack(
    const unsigned char* __restrict__ cmb,
    int* __restrict__ sel)
{
    const int row = blockIdx.x;
    const int tid = threadIdx.x;
    __shared__ unsigned char c0out[256];
    __shared__ int pmax[256];
    __shared__ unsigned sums[256];

    // 32 cm bytes -> 32 bits (mask p >= NCAND-1: pad-false + poison tail)
    const unsigned* cmw = (const unsigned*)(cmb + (size_t)row*ROWPAD);
    unsigned cmbits = 0;
    #pragma unroll
    for (int q = 0; q < 8; ++q) {
        unsigned wrd = cmw[tid*8 + q];
        #pragma unroll
        for (int bb = 0; bb < 4; ++bb) {
            int p = tid*32 + q*4 + bb;
            unsigned bit = ((wrd >> (8*bb)) & 0xffu) ? 1u : 0u;
            if (p >= NCAND-1) bit = 0;
            cmbits |= bit << (q*4 + bb);
        }
    }

    // chunk function: consumed' = cm & ~consumed forgets carry at first cm=0.
    // After the last 0-bit, T trailing (in processing order, i.e. leading in
    // bit position) ones toggle from 0 -> out = T&1. All-ones chunk = identity.
    unsigned inv = ~cmbits;
    unsigned T = (inv == 0u) ? 32u : (unsigned)__clz(inv);
    c0out[tid] = (unsigned char)(T & 1u);
    pmax[tid]  = (inv == 0u) ? -1 : tid;   // last non-identity chunk
    __syncthreads();
    for (int off = 1; off < 256; off <<= 1) {          // inclusive prefix-max
        int v = (tid >= off) ? pmax[tid-off] : -1;
        __syncthreads();
        if (v > pmax[tid]) pmax[tid] = v;
        __syncthreads();
    }
    unsigned carry = 0;
    if (tid > 0) { int m = pmax[tid-1]; if (m >= 0) carry = c0out[m]; }

    // exact merge/valid bits with carry-in
    unsigned cons = carry;
    unsigned validb = 0, mergeb = 0;
    int cnt = 0;
    const int base = tid*32;
    int nelem = NCAND - base; if (nelem > 32) nelem = 32; if (nelem < 0) nelem = 0;
    for (int w = 0; w < nelem; ++w) {
        unsigned bit = (cmbits >> w) & 1u;
        unsigned val = cons ^ 1u;
        unsigned mrg = bit & val;
        validb |= val << w;
        mergeb |= mrg << w;
        cnt += (int)val;
        cons = mrg;
    }

    sums[tid] = (unsigned)cnt;
    __syncthreads();
    for (int off = 1; off < 256; off <<= 1) {
        unsigned v = (tid >= off) ? sums[tid-off] : 0u;
        __syncthreads();
        sums[tid] += v;
        __syncthreads();
    }
    unsigned r = sums[tid] - (unsigned)cnt;
    unsigned total = sums[255];
    int* selrow = sel + (size_t)row*ROWPAD;
    for (int w = 0; w < nelem; ++w) {
        if ((validb >> w) & 1u)
            selrow[r++] = ((base + w) << 1) | (int)((mergeb >> w) & 1u);
    }
    for (int idx = (int)total + tid; idx < ROWPAD; idx += 256)
        selrow[idx] = -1;   // sentinel tail: k_out needs no nvalid
}

// One thread per (slab, channel) computes 16 patch values into an LDS tile
// (row-padded +4 words: write banks (4s+8k+c)&31 -> <=2 lanes/bank, free),
// then the block streams its contiguous 16 KB output range as dwordx4.
__global__ __launch_bounds__(256) void k_out(
    const float* __restrict__ convf,
    const int* __restrict__ sel,
    float* __restrict__ out)
{
    __shared__ float tile[32*132];               // 16.9 KB
    const int t = threadIdx.x;
    const int c = t & 7;
    const int s = t >> 3;                        // 0..31
    const unsigned slab = blockIdx.x*32u + (unsigned)s;  // b*NCAND + n
    const unsigned b = slab / NCAND;
    const unsigned n = slab - b*NCAND;
    const unsigned row = b*NCH + (unsigned)c;

    const int e = sel[(size_t)row*ROWPAD + n];
    float vals[16];
    if (e < 0) {
        #pragma unroll
        for (int k = 0; k < 16; ++k) vals[k] = 0.0f;
    } else {
        const int i = e >> 1;
        const int d = (i >= 3*NW) ? 3 : (i >= 2*NW) ? 2 : (i >= NW) ? 1 : 0;
        const float* cf = convf + (size_t)row*8192 + i + 15*d;  // +d*2048 +(i-d*NW)
        float f[17];
        #pragma unroll
        for (int k = 0; k < 17; ++k) f[k] = cf[k];   // f[16] used only for same-dil merge
        if (e & 1) {
            const int i2 = i + 1;                    // merge at i=NCAND-1 masked in k_pack
            const int d2 = (i2 >= 3*NW) ? 3 : (i2 >= 2*NW) ? 2 : (i2 >= NW) ? 1 : 0;
            if (d2 != d) {                           // cross-dilation neighbor (rare)
                const float* cg = convf + (size_t)row*8192 + i2 + 15*d2;
                #pragma unroll
                for (int k = 0; k < 16; ++k) vals[k] = 0.5f*(f[k] + cg[k]);
            } else {
                #pragma unroll
                for (int k = 0; k < 16; ++k) vals[k] = 0.5f*(f[k] + f[k+1]);
            }
        } else {
            #pragma unroll
            for (int k = 0; k < 16; ++k) vals[k] = f[k];
        }
    }
    float* tr = tile + s*132 + c;
    #pragma unroll
    for (int k = 0; k < 16; ++k) tr[k*8] = vals[k];
    __syncthreads();

    const size_t obase = (size_t)blockIdx.x * 4096;  // block's contiguous 16 KB
    #pragma unroll
    for (int m = 0; m < 4; ++m) {
        int L  = (t + m*256)*4;
        int s2 = L >> 7, j = L & 127;                // 132 words = 33x16B: aligned
        float4 v = *(const float4*)&tile[s2*132 + j];
        *(float4*)&out[obase + L] = v;
    }
}

extern "C" void kernel_launch(void* const* d_in, const int* in_sizes, int n_in,
                              void* d_out, int out_size, void* d_ws, size_t ws_size,
                              hipStream_t stream) {
    const float* seasonal = (const float*)d_in[0];
    const float* conv_w   = (const float*)d_in[1];
    const float* conv_b   = (const float*)d_in[2];
    float* out = (float*)d_out;

    char* ws = (char*)d_ws;
    double*        convd = (double*)(ws);
    float*         convf = (float*)(ws + 16777216);
    unsigned char* cmb   = (unsigned char*)(ws + 25165824);
    int*           sel   = (int*)(ws);          // aliases convd (dead after k_cm)

    hipLaunchKernelGGL(k_conv, dim3(NROWS*ND), dim3(256), 0, stream,
                       seasonal, conv_w, conv_b, convd, convf);
    hipLaunchKernelGGL(k_cm,   dim3(NROWS*ND), dim3(256), 0, stream,
                       convd, cmb);
    hipLaunchKernelGGL(k_pack, dim3(NROWS), dim3(256), 0, stream,
                       cmb, sel);
    // 32 slabs x 8 ch per block; 32*NCAND slabs total -> 8132 blocks exact
    hipLaunchKernelGGL(k_out,  dim3(8132), dim3(256), 0, stream,
                       convf, sel, out);
}